// Round 1
// baseline (63.015 us; speedup 1.0000x reference)
//
#include <hip/hip_runtime.h>

#define WT_L0 8192
#define WT_NT 256

// interp_linear (align_corners=False) read: value of upsampled signal at index i
__device__ __forceinline__ float interp_at(const float* __restrict__ s, int in_len,
                                           float scale, int i) {
    float pos = ((float)i + 0.5f) * scale - 0.5f;
    pos = fminf(fmaxf(pos, 0.0f), (float)(in_len - 1));
    int lo = (int)pos;                       // pos >= 0, floor == trunc
    int hi = min(lo + 1, in_len - 1);
    float w = pos - (float)lo;
    return fmaf(s[hi] - s[lo], w, s[lo]);    // s[lo]*(1-w) + s[hi]*w
}

__global__ __launch_bounds__(WT_NT) void wavelet1d_kernel(
    const float* __restrict__ x,
    const float* __restrict__ w0,
    const float* __restrict__ w1,
    const float* __restrict__ w2,
    float* __restrict__ out)
{
    __shared__ float buf[12288];   // 48 KB, phase-reused
    const int row = blockIdx.x;
    const int tid = threadIdx.x;
    const float* __restrict__ xr = x + (size_t)row * WT_L0;
    float* __restrict__ outr = out + (size_t)row * 3 * WT_L0;

    // broadcast filter taps to registers
    float f0[3], f1[5], f2[7];
    #pragma unroll
    for (int t = 0; t < 3; ++t) f0[t] = w0[t];
    #pragma unroll
    for (int t = 0; t < 5; ++t) f1[t] = w1[t];
    #pragma unroll
    for (int t = 0; t < 7; ++t) f2[t] = w2[t];

    // ---- Phase 1: stage row into LDS (vectorized 16B/lane) ----
    {
        const float4* __restrict__ xr4 = (const float4*)xr;
        float4* row4 = (float4*)buf;
        for (int i = tid; i < WT_L0 / 4; i += WT_NT) row4[i] = xr4[i];
    }
    __syncthreads();

    const float* row_s = buf;                 // [0, 8192)

    // ---- scale 0: conv3 -> out[0] (identity resize) ----
    for (int i = tid; i < WT_L0; i += WT_NT) {
        float acc = 0.f;
        #pragma unroll
        for (int t = 0; t < 3; ++t) {
            int j = i + t - 1;
            float v = (j >= 0 && j < WT_L0) ? row_s[j] : 0.f;
            acc = fmaf(f0[t], v, acc);
        }
        outr[i] = acc;
    }

    // sig1 = avgpool2(row) -> buf[8192:12288)  (4096)
    float* sig1 = buf + 8192;
    for (int i = tid; i < 4096; i += WT_NT)
        sig1[i] = 0.5f * (row_s[2 * i] + row_s[2 * i + 1]);
    __syncthreads();                          // row region now dead

    // ---- scale 1 ----
    // filt1 = conv5(sig1) -> buf[0:4096)
    float* filt1 = buf;
    for (int i = tid; i < 4096; i += WT_NT) {
        float acc = 0.f;
        #pragma unroll
        for (int t = 0; t < 5; ++t) {
            int j = i + t - 2;
            float v = (j >= 0 && j < 4096) ? sig1[j] : 0.f;
            acc = fmaf(f1[t], v, acc);
        }
        filt1[i] = acc;
    }
    __syncthreads();

    // down1 = avgpool2(filt1) -> buf[4096:6144); sig2 = avgpool2(sig1) -> buf[6144:8192)
    float* down1 = buf + 4096;
    float* sig2  = buf + 6144;
    for (int i = tid; i < 2048; i += WT_NT) {
        down1[i] = 0.5f * (filt1[2 * i] + filt1[2 * i + 1]);
        sig2[i]  = 0.5f * (sig1[2 * i] + sig1[2 * i + 1]);
    }
    __syncthreads();

    // coeff1 = interp(down1, 2048 -> 4096) -> buf[8192:12288) (overwrites sig1; sig2 saved)
    float* coeff1 = buf + 8192;
    for (int i = tid; i < 4096; i += WT_NT)
        coeff1[i] = interp_at(down1, 2048, 0.5f, i);
    __syncthreads();

    // out[1] = interp(coeff1, 4096 -> 8192); concurrently filt2 = conv7(sig2) -> buf[0:2048)
    for (int i = tid; i < WT_L0; i += WT_NT)
        outr[WT_L0 + i] = interp_at(coeff1, 4096, 0.5f, i);

    float* filt2 = buf;
    for (int i = tid; i < 2048; i += WT_NT) {
        float acc = 0.f;
        #pragma unroll
        for (int t = 0; t < 7; ++t) {
            int j = i + t - 3;
            float v = (j >= 0 && j < 2048) ? sig2[j] : 0.f;
            acc = fmaf(f2[t], v, acc);
        }
        filt2[i] = acc;
    }
    __syncthreads();

    // ---- scale 2 ----
    // down2 = avgpool2(filt2) -> buf[2048:3072)
    float* down2 = buf + 2048;
    for (int i = tid; i < 1024; i += WT_NT)
        down2[i] = 0.5f * (filt2[2 * i] + filt2[2 * i + 1]);
    __syncthreads();

    // coeff2 = interp(down2, 1024 -> 2048) -> buf[3072:5120)
    float* coeff2 = buf + 3072;
    for (int i = tid; i < 2048; i += WT_NT)
        coeff2[i] = interp_at(down2, 1024, 0.5f, i);
    __syncthreads();

    // out[2] = interp(coeff2, 2048 -> 8192)  (4x upsample)
    for (int i = tid; i < WT_L0; i += WT_NT)
        outr[2 * WT_L0 + i] = interp_at(coeff2, 2048, 0.25f, i);
}

extern "C" void kernel_launch(void* const* d_in, const int* in_sizes, int n_in,
                              void* d_out, int out_size, void* d_ws, size_t ws_size,
                              hipStream_t stream) {
    const float* x  = (const float*)d_in[0];
    const float* w0 = (const float*)d_in[1];
    const float* w1 = (const float*)d_in[2];
    const float* w2 = (const float*)d_in[3];
    float* out = (float*)d_out;

    const int rows = in_sizes[0] / WT_L0;     // B*C = 2048
    wavelet1d_kernel<<<dim3(rows), dim3(WT_NT), 0, stream>>>(x, w0, w1, w2, out);
}

// Round 3
// 54.348 us; speedup vs baseline: 1.1595x; 1.1595x over previous
//
#include <hip/hip_runtime.h>

#define WT_L0 8192
#define WT_NT 512

typedef float f4 __attribute__((ext_vector_type(4)));
typedef float f2 __attribute__((ext_vector_type(2)));

__global__ __launch_bounds__(WT_NT) void wavelet1d_kernel(
    const float* __restrict__ x,
    const float* __restrict__ w0,
    const float* __restrict__ w1,
    const float* __restrict__ w2,
    float* __restrict__ out)
{
    __shared__ float buf[12288];   // 48 KB, phase-reused
    const int row = blockIdx.x;
    const int tid = threadIdx.x;
    const float* __restrict__ xr = x + (size_t)row * WT_L0;
    float* __restrict__ outr = out + (size_t)row * 3 * WT_L0;

    float f0[3], f1[5], f2a[7];
    #pragma unroll
    for (int t = 0; t < 3; ++t) f0[t] = w0[t];
    #pragma unroll
    for (int t = 0; t < 5; ++t) f1[t] = w1[t];
    #pragma unroll
    for (int t = 0; t < 7; ++t) f2a[t] = w2[t];

    // ---------- phase 1: stage row ----------
    {
        const f4* __restrict__ xr4 = (const f4*)xr;
        f4* row4w = (f4*)buf;
        for (int i = tid; i < WT_L0 / 4; i += WT_NT)
            row4w[i] = __builtin_nontemporal_load(&xr4[i]);
    }
    __syncthreads();

    const float* row_s = buf;                     // [0,8192)
    const f4*    row4  = (const f4*)row_s;

    // ---------- scale 0: conv3 -> out[0], and sig1 = avgpool2(row) ----------
    {
        f4* __restrict__ out0_4 = (f4*)outr;
        for (int q = tid; q < 2048; q += WT_NT) {
            int b = 4 * q;
            f4 v = row4[q];
            float lm = (b > 0)        ? row_s[b - 1] : 0.f;
            float rp = (b + 4 < 8192) ? row_s[b + 4] : 0.f;
            f4 o;
            o.x = f0[0]*lm  + f0[1]*v.x + f0[2]*v.y;
            o.y = f0[0]*v.x + f0[1]*v.y + f0[2]*v.z;
            o.z = f0[0]*v.y + f0[1]*v.z + f0[2]*v.w;
            o.w = f0[0]*v.z + f0[1]*v.w + f0[2]*rp;
            __builtin_nontemporal_store(o, &out0_4[q]);
        }
        f4* sig1_4w = (f4*)(buf + 8192);
        for (int j = tid; j < 1024; j += WT_NT) {
            f4 a = row4[2 * j], b4 = row4[2 * j + 1];
            f4 s;
            s.x = 0.5f * (a.x + a.y);   s.y = 0.5f * (a.z + a.w);
            s.z = 0.5f * (b4.x + b4.y); s.w = 0.5f * (b4.z + b4.w);
            sig1_4w[j] = s;
        }
    }
    __syncthreads();   // row region dead below

    const float* sig1   = buf + 8192;             // [8192,12288)
    const f4*    sig1_4 = (const f4*)sig1;

    // ---------- filt1 = conv5(sig1) -> buf[0:4096) ----------
    {
        f4* filt1_4w = (f4*)buf;
        for (int q = tid; q < 1024; q += WT_NT) {
            int b = 4 * q;
            f4 v = sig1_4[q];
            float l2 = (b > 0)        ? sig1[b - 2] : 0.f;
            float l1 = (b > 0)        ? sig1[b - 1] : 0.f;
            float r0 = (b + 4 < 4096) ? sig1[b + 4] : 0.f;
            float r1 = (b + 4 < 4096) ? sig1[b + 5] : 0.f;   // b+5<4096 iff b+4<4096 (b mult of 4)
            f4 o;
            o.x = f1[0]*l2  + f1[1]*l1  + f1[2]*v.x + f1[3]*v.y + f1[4]*v.z;
            o.y = f1[0]*l1  + f1[1]*v.x + f1[2]*v.y + f1[3]*v.z + f1[4]*v.w;
            o.z = f1[0]*v.x + f1[1]*v.y + f1[2]*v.z + f1[3]*v.w + f1[4]*r0;
            o.w = f1[0]*v.y + f1[1]*v.z + f1[2]*v.w + f1[3]*r0  + f1[4]*r1;
            filt1_4w[q] = o;
        }
    }
    __syncthreads();

    const f4* filt1_4 = (const f4*)buf;

    // ---------- down1 = pool(filt1) -> [4096,6144); sig2 = pool(sig1) -> [6144,8192) ----------
    {
        f4* down1_4w = (f4*)(buf + 4096);
        f4* sig2_4w  = (f4*)(buf + 6144);
        for (int j = tid; j < 512; j += WT_NT) {
            f4 a = filt1_4[2 * j], b4 = filt1_4[2 * j + 1];
            f4 d;
            d.x = 0.5f * (a.x + a.y);   d.y = 0.5f * (a.z + a.w);
            d.z = 0.5f * (b4.x + b4.y); d.w = 0.5f * (b4.z + b4.w);
            down1_4w[j] = d;
            f4 c = sig1_4[2 * j], e = sig1_4[2 * j + 1];
            f4 s;
            s.x = 0.5f * (c.x + c.y);  s.y = 0.5f * (c.z + c.w);
            s.z = 0.5f * (e.x + e.y);  s.w = 0.5f * (e.z + e.w);
            sig2_4w[j] = s;
        }
    }
    __syncthreads();   // sig1 dead below (coeff1 overwrites)

    const float* down1 = buf + 4096;
    const float* sig2  = buf + 6144;
    const f4*    sig2_4 = (const f4*)sig2;

    // ---------- coeff1 = up2(down1, 2048->4096) -> [8192,12288) ----------
    {
        f4* coeff1_4w = (f4*)(buf + 8192);
        for (int q = tid; q < 1024; q += WT_NT) {
            int m = 2 * q;
            float dm1 = (m > 0) ? down1[m - 1] : down1[0];
            f2 d01 = *(const f2*)&down1[m];
            float d2  = (m + 2 < 2048) ? down1[m + 2] : down1[2047];
            f4 o;
            o.x = 0.25f * dm1   + 0.75f * d01.x;
            o.y = 0.75f * d01.x + 0.25f * d01.y;
            o.z = 0.25f * d01.x + 0.75f * d01.y;
            o.w = 0.75f * d01.y + 0.25f * d2;
            coeff1_4w[q] = o;
        }
    }
    __syncthreads();

    const float* coeff1 = buf + 8192;

    // ---------- out[1] = up2(coeff1, 4096->8192); filt2 = conv7(sig2) -> [0,2048) ----------
    {
        f4* __restrict__ out1_4 = (f4*)(outr + WT_L0);
        for (int q = tid; q < 2048; q += WT_NT) {
            int m = 2 * q;
            float cm1 = (m > 0) ? coeff1[m - 1] : coeff1[0];
            f2 c01 = *(const f2*)&coeff1[m];
            float c2  = (m + 2 < 4096) ? coeff1[m + 2] : coeff1[4095];
            f4 o;
            o.x = 0.25f * cm1   + 0.75f * c01.x;
            o.y = 0.75f * c01.x + 0.25f * c01.y;
            o.z = 0.25f * c01.x + 0.75f * c01.y;
            o.w = 0.75f * c01.y + 0.25f * c2;
            __builtin_nontemporal_store(o, &out1_4[q]);
        }
        f4* filt2_4w = (f4*)buf;
        for (int q = tid; q < 512; q += WT_NT) {
            int b = 4 * q;
            f4 v = sig2_4[q];
            float l3 = (b > 0) ? sig2[b - 3] : 0.f;
            float l2 = (b > 0) ? sig2[b - 2] : 0.f;
            float l1 = (b > 0) ? sig2[b - 1] : 0.f;
            float r0 = (b + 4 < 2048) ? sig2[b + 4] : 0.f;
            float r1 = (b + 4 < 2048) ? sig2[b + 5] : 0.f;
            float r2 = (b + 4 < 2048) ? sig2[b + 6] : 0.f;
            f4 o;
            o.x = f2a[0]*l3  + f2a[1]*l2  + f2a[2]*l1  + f2a[3]*v.x + f2a[4]*v.y + f2a[5]*v.z + f2a[6]*v.w;
            o.y = f2a[0]*l2  + f2a[1]*l1  + f2a[2]*v.x + f2a[3]*v.y + f2a[4]*v.z + f2a[5]*v.w + f2a[6]*r0;
            o.z = f2a[0]*l1  + f2a[1]*v.x + f2a[2]*v.y + f2a[3]*v.z + f2a[4]*v.w + f2a[5]*r0  + f2a[6]*r1;
            o.w = f2a[0]*v.x + f2a[1]*v.y + f2a[2]*v.z + f2a[3]*v.w + f2a[4]*r0  + f2a[5]*r1  + f2a[6]*r2;
            filt2_4w[q] = o;
        }
    }
    __syncthreads();

    const f4* filt2_4 = (const f4*)buf;

    // ---------- down2 = pool(filt2) -> [2048,3072) ----------
    {
        f4* down2_4w = (f4*)(buf + 2048);
        for (int j = tid; j < 256; j += WT_NT) {
            f4 a = filt2_4[2 * j], b4 = filt2_4[2 * j + 1];
            f4 d;
            d.x = 0.5f * (a.x + a.y);   d.y = 0.5f * (a.z + a.w);
            d.z = 0.5f * (b4.x + b4.y); d.w = 0.5f * (b4.z + b4.w);
            down2_4w[j] = d;
        }
    }
    __syncthreads();

    const float* down2 = buf + 2048;

    // ---------- coeff2 = up2(down2, 1024->2048) -> [3072,5120) ----------
    {
        f4* coeff2_4w = (f4*)(buf + 3072);
        for (int q = tid; q < 512; q += WT_NT) {
            int m = 2 * q;
            float dm1 = (m > 0) ? down2[m - 1] : down2[0];
            f2 d01 = *(const f2*)&down2[m];
            float d2  = (m + 2 < 1024) ? down2[m + 2] : down2[1023];
            f4 o;
            o.x = 0.25f * dm1   + 0.75f * d01.x;
            o.y = 0.75f * d01.x + 0.25f * d01.y;
            o.z = 0.25f * d01.x + 0.75f * d01.y;
            o.w = 0.75f * d01.y + 0.25f * d2;
            coeff2_4w[q] = o;
        }
    }
    __syncthreads();

    const float* coeff2 = buf + 3072;

    // ---------- out[2] = up4(coeff2, 2048->8192) ----------
    {
        f4* __restrict__ out2_4 = (f4*)(outr + 2 * WT_L0);
        for (int q = tid; q < 2048; q += WT_NT) {
            float cm1 = (q > 0) ? coeff2[q - 1] : coeff2[0];
            float c0  = coeff2[q];
            float c1  = (q + 1 < 2048) ? coeff2[q + 1] : coeff2[2047];
            f4 o;
            o.x = 0.375f * cm1 + 0.625f * c0;
            o.y = 0.125f * cm1 + 0.875f * c0;
            o.z = 0.875f * c0  + 0.125f * c1;
            o.w = 0.625f * c0  + 0.375f * c1;
            __builtin_nontemporal_store(o, &out2_4[q]);
        }
    }
}

extern "C" void kernel_launch(void* const* d_in, const int* in_sizes, int n_in,
                              void* d_out, int out_size, void* d_ws, size_t ws_size,
                              hipStream_t stream) {
    const float* x  = (const float*)d_in[0];
    const float* w0 = (const float*)d_in[1];
    const float* w1 = (const float*)d_in[2];
    const float* w2 = (const float*)d_in[3];
    float* out = (float*)d_out;

    const int rows = in_sizes[0] / WT_L0;     // B*C = 2048
    wavelet1d_kernel<<<dim3(rows), dim3(WT_NT), 0, stream>>>(x, w0, w1, w2, out);
}

// Round 4
// 51.725 us; speedup vs baseline: 1.2183x; 1.0507x over previous
//
#include <hip/hip_runtime.h>

#define WT_L0 8192
#define WT_NT 512

typedef float f4 __attribute__((ext_vector_type(4)));
typedef float f2 __attribute__((ext_vector_type(2)));

// LDS layout (floats), peak 10240 = 40 KB -> 4 blocks/CU:
//   sig1   [0,4096)      then coeff1 [0,4096)
//   filt1  [4096,8192)   then filt2  [4096,6144), coeff2 [6144,8192)
//   sig2   [8192,10240)

__global__ __launch_bounds__(WT_NT) void wavelet1d_kernel(
    const float* __restrict__ x,
    const float* __restrict__ w0,
    const float* __restrict__ w1,
    const float* __restrict__ w2,
    float* __restrict__ out)
{
    __shared__ float buf[10240];
    const int row = blockIdx.x;
    const int t = threadIdx.x;
    const float* __restrict__ xr = x + (size_t)row * WT_L0;
    float* __restrict__ outr = out + (size_t)row * 3 * WT_L0;

    float f0[3], f1[5], f2a[7];
    #pragma unroll
    for (int k = 0; k < 3; ++k) f0[k] = w0[k];
    #pragma unroll
    for (int k = 0; k < 5; ++k) f1[k] = w1[k];
    #pragma unroll
    for (int k = 0; k < 7; ++k) f2a[k] = w2[k];

    // ---- P1: conv3 -> out0 (regs, no LDS for row) + pool -> sig1 ----
    {
        const f4* __restrict__ xr4 = (const f4*)xr;
        f4* __restrict__ out0_4 = (f4*)outr;
        f2* sig1_2 = (f2*)buf;
        #pragma unroll
        for (int c = 0; c < 4; ++c) {
            int q = t + 512 * c;                       // f4 index, 0..2047
            f4 v = __builtin_nontemporal_load(&xr4[q]);
            float lm = (q > 0)    ? xr[4 * q - 1] : 0.f;
            float rp = (q < 2047) ? xr[4 * q + 4] : 0.f;
            f4 o;
            o.x = f0[0]*lm  + f0[1]*v.x + f0[2]*v.y;
            o.y = f0[0]*v.x + f0[1]*v.y + f0[2]*v.z;
            o.z = f0[0]*v.y + f0[1]*v.z + f0[2]*v.w;
            o.w = f0[0]*v.z + f0[1]*v.w + f0[2]*rp;
            __builtin_nontemporal_store(o, &out0_4[q]);
            f2 s; s.x = 0.5f * (v.x + v.y); s.y = 0.5f * (v.z + v.w);
            sig1_2[q] = s;                             // sig1[2q..2q+2)
        }
    }
    __syncthreads();

    const float* sig1   = buf;
    const f4*    sig1_4 = (const f4*)sig1;

    // ---- P2: filt1 = conv5(sig1) -> [4096,8192); sig2 = pool(sig1) -> [8192,10240) ----
    {
        f4* filt1_4w = (f4*)(buf + 4096);
        f2* sig2_2   = (f2*)(buf + 8192);
        #pragma unroll
        for (int c = 0; c < 2; ++c) {
            int i = t + 512 * c;                       // f4 index over sig1, 0..1023
            f4 v = sig1_4[i];
            f2 lf = (i > 0)    ? *(const f2*)&sig1[4 * i - 2] : (f2)(0.f);
            f2 rf = (i < 1023) ? *(const f2*)&sig1[4 * i + 4] : (f2)(0.f);
            // sa = { lf.x, lf.y, v.x, v.y, v.z, v.w, rf.x, rf.y }
            f4 o;
            o.x = f1[0]*lf.x + f1[1]*lf.y + f1[2]*v.x  + f1[3]*v.y  + f1[4]*v.z;
            o.y = f1[0]*lf.y + f1[1]*v.x  + f1[2]*v.y  + f1[3]*v.z  + f1[4]*v.w;
            o.z = f1[0]*v.x  + f1[1]*v.y  + f1[2]*v.z  + f1[3]*v.w  + f1[4]*rf.x;
            o.w = f1[0]*v.y  + f1[1]*v.z  + f1[2]*v.w  + f1[3]*rf.x + f1[4]*rf.y;
            filt1_4w[i] = o;
            f2 s; s.x = 0.5f * (v.x + v.y); s.y = 0.5f * (v.z + v.w);
            sig2_2[i] = s;                             // sig2[2i..2i+2)
        }
    }
    __syncthreads();

    const float* filt1   = buf + 4096;
    const f4*    filt1_4 = (const f4*)filt1;

    // ---- P3: coeff1 = up2(pool(filt1)) fused -> [0,4096) (sig1 dead) ----
    {
        f4* coeff1_4w = (f4*)buf;
        #pragma unroll
        for (int c = 0; c < 2; ++c) {
            int i = t + 512 * c;                       // f4 index over filt1, 0..1023
            f4 v = filt1_4[i];
            float d1 = 0.5f * (v.x + v.y);
            float d2 = 0.5f * (v.z + v.w);
            float dm, dp;
            if (i > 0)    { f2 lf = *(const f2*)&filt1[4 * i - 2]; dm = 0.5f * (lf.x + lf.y); }
            else          { dm = d1; }                 // replicate edge (interp clamp)
            if (i < 1023) { f2 rf = *(const f2*)&filt1[4 * i + 4]; dp = 0.5f * (rf.x + rf.y); }
            else          { dp = d2; }
            f4 o;
            o.x = 0.25f * dm + 0.75f * d1;
            o.y = 0.75f * d1 + 0.25f * d2;
            o.z = 0.25f * d1 + 0.75f * d2;
            o.w = 0.75f * d2 + 0.25f * dp;
            coeff1_4w[i] = o;                          // coeff1[4i..4i+4)
        }
    }
    __syncthreads();

    const float* coeff1 = buf;
    const float* sig2   = buf + 8192;
    const f4*    sig2_4 = (const f4*)sig2;

    // ---- P4: out1 = up2(coeff1) -> global; filt2 = conv7(sig2) -> [4096,6144) ----
    {
        f4* __restrict__ out1_4 = (f4*)(outr + WT_L0);
        #pragma unroll
        for (int c = 0; c < 4; ++c) {
            int q = t + 512 * c;                       // out1 f4 index, 0..2047
            f2 c01 = *(const f2*)&coeff1[2 * q];
            float cm = (q > 0)    ? coeff1[2 * q - 1] : coeff1[0];
            float cp = (q < 2047) ? coeff1[2 * q + 2] : coeff1[4095];
            f4 o;
            o.x = 0.25f * cm    + 0.75f * c01.x;
            o.y = 0.75f * c01.x + 0.25f * c01.y;
            o.z = 0.25f * c01.x + 0.75f * c01.y;
            o.w = 0.75f * c01.y + 0.25f * cp;
            __builtin_nontemporal_store(o, &out1_4[q]);
        }
        // filt2 = conv7(sig2): one f4 per thread (i = t over 0..511)
        f4* filt2_4w = (f4*)(buf + 4096);
        {
            int i = t;
            f4 v = sig2_4[i];
            float l3 = 0.f, l2 = 0.f, l1 = 0.f, r0 = 0.f, r1 = 0.f, r2 = 0.f;
            if (i > 0) {
                f2 lf = *(const f2*)&sig2[4 * i - 2];
                l3 = sig2[4 * i - 3]; l2 = lf.x; l1 = lf.y;
            }
            if (i < 511) {
                f2 rf = *(const f2*)&sig2[4 * i + 4];
                r0 = rf.x; r1 = rf.y; r2 = sig2[4 * i + 6];
            }
            f4 o;
            o.x = f2a[0]*l3  + f2a[1]*l2  + f2a[2]*l1  + f2a[3]*v.x + f2a[4]*v.y + f2a[5]*v.z + f2a[6]*v.w;
            o.y = f2a[0]*l2  + f2a[1]*l1  + f2a[2]*v.x + f2a[3]*v.y + f2a[4]*v.z + f2a[5]*v.w + f2a[6]*r0;
            o.z = f2a[0]*l1  + f2a[1]*v.x + f2a[2]*v.y + f2a[3]*v.z + f2a[4]*v.w + f2a[5]*r0  + f2a[6]*r1;
            o.w = f2a[0]*v.x + f2a[1]*v.y + f2a[2]*v.z + f2a[3]*v.w + f2a[4]*r0  + f2a[5]*r1  + f2a[6]*r2;
            filt2_4w[i] = o;
        }
    }
    __syncthreads();

    const float* filt2   = buf + 4096;
    const f4*    filt2_4 = (const f4*)filt2;

    // ---- P5: coeff2 = up2(pool(filt2)) fused -> [6144,8192) ----
    {
        f4* coeff2_4w = (f4*)(buf + 6144);
        int i = t;                                     // f4 index over filt2, 0..511
        f4 v = filt2_4[i];
        float d1 = 0.5f * (v.x + v.y);
        float d2 = 0.5f * (v.z + v.w);
        float dm, dp;
        if (i > 0)   { f2 lf = *(const f2*)&filt2[4 * i - 2]; dm = 0.5f * (lf.x + lf.y); }
        else         { dm = d1; }
        if (i < 511) { f2 rf = *(const f2*)&filt2[4 * i + 4]; dp = 0.5f * (rf.x + rf.y); }
        else         { dp = d2; }
        f4 o;
        o.x = 0.25f * dm + 0.75f * d1;
        o.y = 0.75f * d1 + 0.25f * d2;
        o.z = 0.25f * d1 + 0.75f * d2;
        o.w = 0.75f * d2 + 0.25f * dp;
        coeff2_4w[i] = o;                              // coeff2[4i..4i+4)
    }
    __syncthreads();

    const float* coeff2 = buf + 6144;

    // ---- P6: out2 = up4(coeff2) -> global ----
    {
        f4* __restrict__ out2_4 = (f4*)(outr + 2 * WT_L0);
        #pragma unroll
        for (int c = 0; c < 4; ++c) {
            int q = t + 512 * c;                       // coeff2 index / out2 f4 index, 0..2047
            float c0 = coeff2[q];
            float cm = (q > 0)    ? coeff2[q - 1] : c0;
            float cp = (q < 2047) ? coeff2[q + 1] : c0;
            f4 o;
            o.x = 0.375f * cm + 0.625f * c0;
            o.y = 0.125f * cm + 0.875f * c0;
            o.z = 0.875f * c0 + 0.125f * cp;
            o.w = 0.625f * c0 + 0.375f * cp;
            __builtin_nontemporal_store(o, &out2_4[q]);
        }
    }
}

extern "C" void kernel_launch(void* const* d_in, const int* in_sizes, int n_in,
                              void* d_out, int out_size, void* d_ws, size_t ws_size,
                              hipStream_t stream) {
    const float* x  = (const float*)d_in[0];
    const float* w0 = (const float*)d_in[1];
    const float* w1 = (const float*)d_in[2];
    const float* w2 = (const float*)d_in[3];
    float* out = (float*)d_out;

    const int rows = in_sizes[0] / WT_L0;     // B*C = 2048
    wavelet1d_kernel<<<dim3(rows), dim3(WT_NT), 0, stream>>>(x, w0, w1, w2, out);
}